// Round 13
// baseline (2123.056 us; speedup 1.0000x reference)
//
#include <hip/hip_runtime.h>
#include <stdint.h>

// Problem constants
#define B_  256
#define S_  512
#define E_  100
#define H_  512
#define G_  2048          // 4H
#define KH_ 512

typedef _Float16 half8 __attribute__((ext_vector_type(8)));
typedef float    f32x4 __attribute__((ext_vector_type(4)));
typedef unsigned uint4v __attribute__((ext_vector_type(4)));
union V16 { f32x4 f; half8 h; unsigned long long q[2]; };

#define MFMA16 __builtin_amdgcn_mfma_f32_16x16x32_f16

// ws layout (bytes) — identical envelope to r7
#define OFF_WC   0u          // Wc [c32][w4][s20][L64][e8] f16  : 2,621,440
#define OFF_HBT  2621440u    // hbt [2][16 r][16 b][512] u32    : 1,048,576
#define OFF_XB3  3670016u    // xb3 [t512][rg16][j3][L64][e8]   : 25,165,824
#define OFF_XTL  28835840u   // xtl [t512][b256][e4] f16        : 1,048,576
#define OFF_BIAS 29884416u   // [G] f32                         : 8,192
#define WS_NEED  29892608u

// LDS carve (dynamic)
#define LDS_W   65536        // [w4][kt16][L64][16B] — W h-part, shared by both streams
#define LDS_A   16384        // h A-tile [16 rows][512 halfs], XOR-swizzled (time-shared A/B)
#define LDS_G   4352         // float[4][16][17]
#define LDS_TOT (LDS_W + LDS_A + LDS_G)   // 86,272

// ---- 8x dwordx4 LLC-direct loads, issue-only (no waitcnt) ----
#define GL8(v, b)                                                       \
  asm volatile(                                                         \
    "global_load_dwordx4 %0, %8, off sc0 sc1\n\t"                       \
    "global_load_dwordx4 %1, %9, off sc0 sc1\n\t"                       \
    "global_load_dwordx4 %2, %10, off sc0 sc1\n\t"                      \
    "global_load_dwordx4 %3, %11, off sc0 sc1\n\t"                      \
    "global_load_dwordx4 %4, %12, off sc0 sc1\n\t"                      \
    "global_load_dwordx4 %5, %13, off sc0 sc1\n\t"                      \
    "global_load_dwordx4 %6, %14, off sc0 sc1\n\t"                      \
    "global_load_dwordx4 %7, %15, off sc0 sc1"                          \
    : "=&v"(v[0]), "=&v"(v[1]), "=&v"(v[2]), "=&v"(v[3]),               \
      "=&v"(v[4]), "=&v"(v[5]), "=&v"(v[6]), "=&v"(v[7])                \
    : "v"(b), "v"(b + 4096), "v"(b + 8192), "v"(b + 12288),             \
      "v"(b + 16384), "v"(b + 20480), "v"(b + 24576), "v"(b + 28672)    \
    : "memory")

// ---- same loads + drain (retry path) ----
#define GL8W(v, b)                                                      \
  asm volatile(                                                         \
    "global_load_dwordx4 %0, %8, off sc0 sc1\n\t"                       \
    "global_load_dwordx4 %1, %9, off sc0 sc1\n\t"                       \
    "global_load_dwordx4 %2, %10, off sc0 sc1\n\t"                      \
    "global_load_dwordx4 %3, %11, off sc0 sc1\n\t"                      \
    "global_load_dwordx4 %4, %12, off sc0 sc1\n\t"                      \
    "global_load_dwordx4 %5, %13, off sc0 sc1\n\t"                      \
    "global_load_dwordx4 %6, %14, off sc0 sc1\n\t"                      \
    "global_load_dwordx4 %7, %15, off sc0 sc1\n\t"                      \
    "s_waitcnt vmcnt(0)"                                                \
    : "=&v"(v[0]), "=&v"(v[1]), "=&v"(v[2]), "=&v"(v[3]),               \
      "=&v"(v[4]), "=&v"(v[5]), "=&v"(v[6]), "=&v"(v[7])                \
    : "v"(b), "v"(b + 4096), "v"(b + 8192), "v"(b + 12288),             \
      "v"(b + 16384), "v"(b + 20480), "v"(b + 24576), "v"(b + 28672)    \
    : "memory")

// drain + tie registers (dependency-carried: checks can't hoist above)
#define VWAIT8(v)                                                       \
  asm volatile("s_waitcnt vmcnt(0)"                                     \
    : "+v"(v[0]), "+v"(v[1]), "+v"(v[2]), "+v"(v[3]),                   \
      "+v"(v[4]), "+v"(v[5]), "+v"(v[6]), "+v"(v[7]) :: "memory")

static __device__ __forceinline__ void validate_retry(uint4v* v, const char* base,
                                                      unsigned tag) {
    VWAIT8(v);
    __builtin_amdgcn_sched_barrier(0);
    unsigned bad = 0;
#pragma unroll
    for (int i = 0; i < 8; ++i)
#pragma unroll
        for (int k = 0; k < 4; ++k) bad |= (v[i][k] ^ tag) & 0xFFFFu;
    int r = 0;
    while (__any(bad != 0)) {
        if (++r > 2000000) break;          // safety valve
        GL8W(v, base);
        bad = 0;
#pragma unroll
        for (int i = 0; i < 8; ++i)
#pragma unroll
            for (int k = 0; k < 4; ++k) bad |= (v[i][k] ^ tag) & 0xFFFFu;
    }
    __builtin_amdgcn_sched_barrier(0);
}

// ---------------------------------------------------------------- prep: W (fragment-major) + bias
// Wc idx = (((c*4 + w)*20 + s)*64 + L)*8 + e ; gate-col g = w*512 + c*16 + (L&15)
// k(s): s<16 -> h k=s*32+kl ; s=16..18 -> x k=(s-16)*32+kl ; s=19 -> x k=96+kl
__global__ void prep_wc5(const float* __restrict__ Wih, const float* __restrict__ Whh,
                         const float* __restrict__ bih, const float* __restrict__ bhh,
                         _Float16* __restrict__ Wc, float* __restrict__ bias) {
    int idx = blockIdx.x * 256 + threadIdx.x;     // < 1,310,720
    int e  = idx & 7;
    int L  = (idx >> 3) & 63;
    int q  = idx >> 9;                            // < 2560
    int s  = q % 20;
    int r1 = q / 20;                              // < 128
    int w  = r1 & 3;
    int c  = r1 >> 2;                             // 0..31
    int g  = (w << 9) + (c << 4) + (L & 15);
    int kl = ((L >> 4) << 3) + e;
    float v = 0.f;
    if (s < 16) {
        v = Whh[g * KH_ + (s << 5) + kl];
    } else {
        int xk = (s < 19) ? ((s - 16) << 5) + kl : 96 + kl;
        if (xk < E_) v = Wih[g * E_ + xk];
    }
    Wc[idx] = (_Float16)v;
    if (idx < G_) bias[idx] = bih[idx] + bhh[idx];
}

// ---------------------------------------------------------------- prep: x main (k 0..95, fragment-major)
__global__ void prep_x3(const int* __restrict__ sent, const float* __restrict__ emb,
                        _Float16* __restrict__ xb3) {
    size_t idx = (size_t)blockIdx.x * 256 + threadIdx.x;   // < 12,582,912
    int e  = (int)(idx & 7);
    int L  = (int)((idx >> 3) & 63);
    int q  = (int)(idx >> 9);
    int j  = q % 3;
    int qq = q / 3;
    int rg = qq & 15;
    int t  = qq >> 4;
    int b  = (rg << 4) + (L & 15);
    int k  = (j << 5) + ((L >> 4) << 3) + e;     // < 96 < E_
    int tok = sent[b * S_ + t];
    xb3[idx] = (_Float16)emb[(size_t)tok * E_ + k];
}

// ---------------------------------------------------------------- prep: x tail (k 96..99)
__global__ void prep_xtail(const int* __restrict__ sent, const float* __restrict__ emb,
                           _Float16* __restrict__ xtl) {
    int idx = blockIdx.x * 256 + threadIdx.x;    // < 524,288
    int e = idx & 3;
    int b = (idx >> 2) & 255;
    int t = idx >> 10;
    int tok = sent[b * S_ + t];
    xtl[idx] = (_Float16)emb[(size_t)tok * E_ + 96 + e];
}

// ---------------------------------------------------------------- persistent LSTM
// 256 blocks, each owns TWO streams: (row rp, ctile c16) and (row rp+8, c16) —
// same W slice (LDS-shared). Per super-step: phase A (row rp, step t) then
// phase B (rp+8, step t). Each phase's tagged h loads are ISSUED one phase
// ahead (slack ≈ one phase of compute) and validated via dependency-carried
// waitcnt; retry with fresh LLC loads covers any skew. Publish: fused tagged
// u32 (h16|tag16), relaxed agent store, fire-and-forget (no drains anywhere).
__global__ __launch_bounds__(256, 1) void lstm_persist(
    const _Float16* __restrict__ Wc, unsigned* __restrict__ hbt,
    const _Float16* __restrict__ xb3, const _Float16* __restrict__ xtl,
    const float* __restrict__ bias, float* __restrict__ out)
{
    extern __shared__ __align__(16) char smem[];
    char* wl = smem;                       // W h-part [w][kt][L][16B]
    char* al = smem + LDS_W;               // A tile (swizzled, time-shared A/B)
    float (*gbuf)[16][17] = reinterpret_cast<float(*)[16][17]>(smem + LDS_W + LDS_A);

    const int tid = threadIdx.x;
    const int L   = tid & 63;
    const int w   = tid >> 6;              // wave = gate type (0:i 1:f 2:g 3:o)
    const int bx  = blockIdx.x;
    const int rp  = bx & 7;                // row-pair id (XCD heuristic grouping)
    const int c16 = bx >> 3;               // hcol-tile 0..31 (16 cols)
    const int rA  = rp, rB = rp + 8;
    const int hcol0 = c16 << 4;

    // ---- W preload: s 0..15 (h) -> LDS (wave-private region); s 16..19 (x) -> regs
    const _Float16* wp = Wc + (size_t)((c16 << 2) + w) * (20 * 512) + (L << 3);
#pragma unroll
    for (int s = 0; s < 16; ++s)
        *reinterpret_cast<f32x4*>(wl + (((w << 4) + s) << 10) + (L << 4)) =
            *reinterpret_cast<const f32x4*>(wp + (s << 9));
    V16 wx[4];
#pragma unroll
    for (int j = 0; j < 4; ++j)
        wx[j].f = *reinterpret_cast<const f32x4*>(wp + ((16 + j) << 9));

    // ---- per-thread elementwise mapping: (b = tid>>4, j = tid&15), 1 value/stream
    const int eb = tid >> 4;
    const int ej = tid & 15;
    const int hcol = hcol0 + ej;
    const float bi = bias[hcol], bf = bias[512 + hcol];
    const float bg = bias[1024 + hcol], bo = bias[1536 + hcol];
    float csA = 0.f, csB = 0.f;

    const int arow = L & 15;
    const int agrp = L >> 4;
    const int ard  = arow << 10;
    const int asw  = (arow & 7) << 4;

    // ---- x fragments t=0, both streams
    V16 xfA[3], xtA, xfB[3], xtB, xnA[3], xntA, xnB[3], xntB;
    {
        const _Float16* xpA = xb3 + ((size_t)rA * 3) * 512 + (L << 3);
        const _Float16* xpB = xb3 + ((size_t)rB * 3) * 512 + (L << 3);
#pragma unroll
        for (int j = 0; j < 3; ++j) {
            xfA[j].f = *reinterpret_cast<const f32x4*>(xpA + j * 512);
            xfB[j].f = *reinterpret_cast<const f32x4*>(xpB + j * 512);
        }
        unsigned long long tvA = *reinterpret_cast<const unsigned long long*>(
            xtl + (size_t)(rA * 16 + arow) * 4);
        unsigned long long tvB = *reinterpret_cast<const unsigned long long*>(
            xtl + (size_t)(rB * 16 + arow) * 4);
        xtA.q[0] = (agrp == 0) ? tvA : 0ull;  xtA.q[1] = 0ull;
        xtB.q[0] = (agrp == 0) ? tvB : 0ull;  xtB.q[1] = 0ull;
    }

    uint4v vA[8] = {}, vB[8] = {};

    // staging helper values
#define STAGE8(v)                                                            \
    do {                                                                     \
        _Pragma("unroll")                                                    \
        for (int i = 0; i < 8; ++i) {                                        \
            int b_ = (i << 1) + (tid >> 7);                                  \
            unsigned lo = (v[i][0] >> 16) | (v[i][1] & 0xFFFF0000u);         \
            unsigned hi = (v[i][2] >> 16) | (v[i][3] & 0xFFFF0000u);         \
            unsigned long long val = ((unsigned long long)hi << 32) | lo;    \
            *reinterpret_cast<unsigned long long*>(                          \
                al + (b_ << 10) +                                            \
                (((((tid & 127) >> 1) << 4) ^ ((b_ & 7) << 4))) +            \
                ((tid & 1) << 3)) = val;                                     \
        }                                                                    \
    } while (0)

    for (int t = 0; t < S_; ++t) {
        const char* baseA_t  = (const char*)hbt + ((size_t)(t & 1) << 19)
                             + ((size_t)rA << 15) + (tid << 4);
        const char* baseB_t  = (const char*)hbt + ((size_t)(t & 1) << 19)
                             + ((size_t)rB << 15) + (tid << 4);
        const unsigned tag = (unsigned)t;

        // ================= PHASE A (row rA, step t) =================
        if (t > 0) { validate_retry(vA, baseA_t, tag); STAGE8(vA); }
        __syncthreads();                   // A tile ready / gbuf free
        if (t > 0) { GL8(vB, baseB_t); __builtin_amdgcn_sched_barrier(0); }

        {
            f32x4 a0 = {0,0,0,0}, a1 = {0,0,0,0};
#pragma unroll
            for (int j = 0; j < 4; ++j) {
                half8 a = (j < 3) ? xfA[j].h : xtA.h;
                if (j & 1) a1 = MFMA16(a, wx[j].h, a1, 0, 0, 0);
                else       a0 = MFMA16(a, wx[j].h, a0, 0, 0, 0);
            }
            if (t > 0) {
#pragma unroll
                for (int kt = 0; kt < 16; ++kt) {
                    V16 av, bv;
                    av.f = *reinterpret_cast<const f32x4*>(
                        al + ard + ((((kt << 2) + agrp) << 4) ^ asw));
                    bv.f = *reinterpret_cast<const f32x4*>(
                        wl + (((w << 4) + kt) << 10) + (L << 4));
                    if (kt & 1) a1 = MFMA16(av.h, bv.h, a1, 0, 0, 0);
                    else        a0 = MFMA16(av.h, bv.h, a0, 0, 0, 0);
                }
            }
            f32x4 g = a0 + a1;
            const int grb = agrp << 2, gc = L & 15;
#pragma unroll
            for (int rr = 0; rr < 4; ++rr) gbuf[w][grb + rr][gc] = g[rr];
        }
        __syncthreads();                   // gates ready

        {
            float iv = gbuf[0][eb][ej] + bi, fv = gbuf[1][eb][ej] + bf;
            float gv = gbuf[2][eb][ej] + bg, ov = gbuf[3][eb][ej] + bo;
            float si = 1.f / (1.f + __expf(-iv));
            float sf = 1.f / (1.f + __expf(-fv));
            float so = 1.f / (1.f + __expf(-ov));
            float tg = tanhf(gv);
            csA = sf * csA + si * tg;
            float hv = so * tanhf(csA);
            if (t == S_ - 1) {
                out[(size_t)(rA * 16 + eb) * H_ + hcol] = hv;
            } else {
                _Float16 hh = (_Float16)hv;
                unsigned word = ((unsigned)*(unsigned short*)&hh << 16)
                              | (unsigned)(t + 1);
                __hip_atomic_store(hbt + ((size_t)((t + 1) & 1) << 17)
                                       + ((size_t)rA << 13) + (eb << 9) + hcol,
                                   word, __ATOMIC_RELAXED, __HIP_MEMORY_SCOPE_AGENT);
            }
        }

        // ================= PHASE B (row rB, step t) =================
        if (t > 0) { validate_retry(vB, baseB_t, tag); STAGE8(vB); }
        __syncthreads();                   // B tile ready / gbuf free
        if (t < S_ - 1) {                  // issue vA for step t+1 (peers publish ~now)
            const char* baseA_n = (const char*)hbt + ((size_t)((t + 1) & 1) << 19)
                                + ((size_t)rA << 15) + (tid << 4);
            GL8(vA, baseA_n);
            __builtin_amdgcn_sched_barrier(0);
        }
        // next-step x prefetch (both streams; flight ≈ one phase, no drains follow)
        {
            const int tn = (t + 1) & (S_ - 1);
            const _Float16* xpA = xb3 + (((size_t)tn * 16 + rA) * 3) * 512 + (L << 3);
            const _Float16* xpB = xb3 + (((size_t)tn * 16 + rB) * 3) * 512 + (L << 3);
#pragma unroll
            for (int j = 0; j < 3; ++j) {
                xnA[j].f = *reinterpret_cast<const f32x4*>(xpA + j * 512);
                xnB[j].f = *reinterpret_cast<const f32x4*>(xpB + j * 512);
            }
            unsigned long long tvA = *reinterpret_cast<const unsigned long long*>(
                xtl + ((size_t)tn * 256 + rA * 16 + arow) * 4);
            unsigned long long tvB = *reinterpret_cast<const unsigned long long*>(
                xtl + ((size_t)tn * 256 + rB * 16 + arow) * 4);
            xntA.q[0] = (agrp == 0) ? tvA : 0ull;  xntA.q[1] = 0ull;
            xntB.q[0] = (agrp == 0) ? tvB : 0ull;  xntB.q[1] = 0ull;
        }

        {
            f32x4 a0 = {0,0,0,0}, a1 = {0,0,0,0};
#pragma unroll
            for (int j = 0; j < 4; ++j) {
                half8 a = (j < 3) ? xfB[j].h : xtB.h;
                if (j & 1) a1 = MFMA16(a, wx[j].h, a1, 0, 0, 0);
                else       a0 = MFMA16(a, wx[j].h, a0, 0, 0, 0);
            }
            if (t > 0) {
#pragma unroll
                for (int kt = 0; kt < 16; ++kt) {
                    V16 av, bv;
                    av.f = *reinterpret_cast<const f32x4*>(
                        al + ard + ((((kt << 2) + agrp) << 4) ^ asw));
                    bv.f = *reinterpret_cast<const f32x4*>(
                        wl + (((w << 4) + kt) << 10) + (L << 4));
                    if (kt & 1) a1 = MFMA16(av.h, bv.h, a1, 0, 0, 0);
                    else        a0 = MFMA16(av.h, bv.h, a0, 0, 0, 0);
                }
            }
            f32x4 g = a0 + a1;
            const int grb = agrp << 2, gc = L & 15;
#pragma unroll
            for (int rr = 0; rr < 4; ++rr) gbuf[w][grb + rr][gc] = g[rr];
        }
        __syncthreads();                   // gates ready

        {
            float iv = gbuf[0][eb][ej] + bi, fv = gbuf[1][eb][ej] + bf;
            float gv = gbuf[2][eb][ej] + bg, ov = gbuf[3][eb][ej] + bo;
            float si = 1.f / (1.f + __expf(-iv));
            float sf = 1.f / (1.f + __expf(-fv));
            float so = 1.f / (1.f + __expf(-ov));
            float tg = tanhf(gv);
            csB = sf * csB + si * tg;
            float hv = so * tanhf(csB);
            if (t == S_ - 1) {
                out[(size_t)(rB * 16 + eb) * H_ + hcol] = hv;
            } else {
                _Float16 hh = (_Float16)hv;
                unsigned word = ((unsigned)*(unsigned short*)&hh << 16)
                              | (unsigned)(t + 1);
                __hip_atomic_store(hbt + ((size_t)((t + 1) & 1) << 17)
                                       + ((size_t)rB << 13) + (eb << 9) + hcol,
                                   word, __ATOMIC_RELAXED, __HIP_MEMORY_SCOPE_AGENT);
            }
        }

        // rotate x prefetch
#pragma unroll
        for (int j = 0; j < 3; ++j) { xfA[j] = xnA[j]; xfB[j] = xnB[j]; }
        xtA = xntA;  xtB = xntB;
    }
#undef STAGE8
}

// ---------------------------------------------------------------- launch
extern "C" void kernel_launch(void* const* d_in, const int* in_sizes, int n_in,
                              void* d_out, int out_size, void* d_ws, size_t ws_size,
                              hipStream_t stream) {
    (void)in_sizes; (void)n_in; (void)out_size;
    if (ws_size < WS_NEED) return;

    const int*   sent = (const int*)d_in[0];
    const float* emb  = (const float*)d_in[1];
    const float* Wih  = (const float*)d_in[2];
    const float* Whh  = (const float*)d_in[3];
    const float* bih  = (const float*)d_in[4];
    const float* bhh  = (const float*)d_in[5];

    char* ws = (char*)d_ws;
    _Float16* Wc   = (_Float16*)(ws + OFF_WC);
    unsigned* hbt  = (unsigned*)(ws + OFF_HBT);
    _Float16* xb3  = (_Float16*)(ws + OFF_XB3);
    _Float16* xtl  = (_Float16*)(ws + OFF_XTL);
    float*    bias = (float*)(ws + OFF_BIAS);

    (void)hipFuncSetAttribute(reinterpret_cast<const void*>(lstm_persist),
                              hipFuncAttributeMaxDynamicSharedMemorySize, LDS_TOT);

    (void)hipMemsetAsync(hbt, 0, 1048576, stream);

    prep_wc5<<<5120, 256, 0, stream>>>(Wih, Whh, bih, bhh, Wc, bias);
    prep_x3<<<49152, 256, 0, stream>>>(sent, emb, xb3);
    prep_xtail<<<2048, 256, 0, stream>>>(sent, emb, xtl);
    lstm_persist<<<256, 256, LDS_TOT, stream>>>(Wc, hbt, xb3, xtl, bias, (float*)d_out);
}

// Round 14
// 1306.889 us; speedup vs baseline: 1.6245x; 1.6245x over previous
//
#include <hip/hip_runtime.h>
#include <stdint.h>

// Problem constants
#define B_  256
#define S_  512
#define E_  100
#define H_  512
#define G_  2048          // 4H
#define KH_ 512

typedef _Float16 half8 __attribute__((ext_vector_type(8)));
typedef float    f32x4 __attribute__((ext_vector_type(4)));
union V16 { f32x4 f; half8 h; unsigned long long q[2]; };

// LDS-only barrier: ds_writes visible, but NO vmcnt drain (raw s_barrier has
// no implicit waitcnt — avoids serializing on in-flight HBM prefetch / publish)
#define BAR_LGKM()                                                  \
    do {                                                            \
        asm volatile("s_waitcnt lgkmcnt(0)" ::: "memory");          \
        __builtin_amdgcn_s_barrier();                               \
        __builtin_amdgcn_sched_barrier(0);                          \
    } while (0)

// ws layout (bytes)
#define OFF_WC   0u          // Wc [c16][w4][n2][s20][L64][e8] f16 : 2,621,440
#define OFF_HBT  2621440u    // hbt [2][256 b][256 cp] u64 tagged-h : 1,048,576
#define OFF_XB3  3670016u    // xb3 [t512][rg16][j3][L64][e8] f16   : 25,165,824
#define OFF_XTL  28835840u   // xtl [t512][b256][e4] f16            : 1,048,576
#define OFF_BIAS 29884416u   // [G] f32                             : 8,192
#define WS_NEED  29892608u

// LDS carve (dynamic) — full W h-part in LDS
#define LDS_W   131072       // [w4][n2][kt16][L64][16B]
#define LDS_A   16384        // h A-tile [16 rows][512 halfs], XOR-swizzled
#define LDS_G   8448         // float[4][16][33]
#define LDS_TOT (LDS_W + LDS_A + LDS_G)   // 155,904

// ---------------------------------------------------------------- prep: W (fragment-major) + bias
__global__ void prep_wc4(const float* __restrict__ Wih, const float* __restrict__ Whh,
                         const float* __restrict__ bih, const float* __restrict__ bhh,
                         _Float16* __restrict__ Wc, float* __restrict__ bias) {
    int idx = blockIdx.x * 256 + threadIdx.x;     // < 1,310,720
    int e  = idx & 7;
    int L  = (idx >> 3) & 63;
    int q  = idx >> 9;                            // < 2560
    int s  = q % 20;
    int qq = q / 20;
    int n  = qq & 1;
    int w  = (qq >> 1) & 3;
    int c  = qq >> 3;
    int g  = (w << 9) + (c << 5) + (n << 4) + (L & 15);
    int kl = ((L >> 4) << 3) + e;
    float v = 0.f;
    if (s < 16) {
        v = Whh[g * KH_ + (s << 5) + kl];
    } else {
        int xk = (s < 19) ? ((s - 16) << 5) + kl : 96 + kl;
        if (xk < E_) v = Wih[g * E_ + xk];
    }
    Wc[idx] = (_Float16)v;
    if (idx < G_) bias[idx] = bih[idx] + bhh[idx];
}

// ---------------------------------------------------------------- prep: x main (k 0..95, fragment-major)
__global__ void prep_x3(const int* __restrict__ sent, const float* __restrict__ emb,
                        _Float16* __restrict__ xb3) {
    size_t idx = (size_t)blockIdx.x * 256 + threadIdx.x;   // < 12,582,912
    int e  = (int)(idx & 7);
    int L  = (int)((idx >> 3) & 63);
    int q  = (int)(idx >> 9);
    int j  = q % 3;
    int qq = q / 3;
    int rg = qq & 15;
    int t  = qq >> 4;
    int b  = (rg << 4) + (L & 15);
    int k  = (j << 5) + ((L >> 4) << 3) + e;     // < 96 < E_
    int tok = sent[b * S_ + t];
    xb3[idx] = (_Float16)emb[(size_t)tok * E_ + k];
}

// ---------------------------------------------------------------- prep: x tail (k 96..99)
__global__ void prep_xtail(const int* __restrict__ sent, const float* __restrict__ emb,
                           _Float16* __restrict__ xtl) {
    int idx = blockIdx.x * 256 + threadIdx.x;    // < 524,288
    int e = idx & 3;
    int b = (idx >> 2) & 255;
    int t = idx >> 10;
    int tok = sent[b * S_ + t];
    xtl[idx] = (_Float16)emb[(size_t)tok * E_ + 96 + e];
}

// ---------------------------------------------------------------- persistent LSTM
// r12 structure + two changes: (1) both barriers are LDS-only (raw s_barrier,
// lgkmcnt drain only) so in-flight HBM x-prefetch and publish stores are never
// drained; (2) x prefetch issued BEFORE barrier 1 so its flight spans the
// whole h-MFMA + elementwise phase (no consumption stall). Fused tagged u64
// publish (fire-and-forget), retry-validate consume — unchanged from r7.
__global__ __launch_bounds__(256, 1) void lstm_persist(
    const _Float16* __restrict__ Wc, unsigned long long* __restrict__ hbt,
    const _Float16* __restrict__ xb3, const _Float16* __restrict__ xtl,
    const float* __restrict__ bias, float* __restrict__ out)
{
    extern __shared__ __align__(16) char smem[];
    char* wl = smem;                       // W h-part fragments
    char* al = smem + LDS_W;               // A tile (swizzled)
    float (*gbuf)[16][33] = reinterpret_cast<float(*)[16][33]>(smem + LDS_W + LDS_A);

    const int tid = threadIdx.x;
    const int L   = tid & 63;
    const int w   = tid >> 6;              // wave = gate type (0:i 1:f 2:g 3:o)
    const int bx  = blockIdx.x;
    const int xcd = bx & 7;                // XCD-aware swizzle (perf heuristic)
    const int kk_ = bx >> 3;
    const int r   = (xcd << 1) | (kk_ >> 4);   // batch-row 0..15
    const int c   = kk_ & 15;                  // hcol-tile 0..15
    const int brow0 = r << 4;
    const int hcol0 = c << 5;

    // ---- W preload: slots 0..15 (h) -> LDS; slots 16..19 (x) -> regs
    const _Float16* wp0 = Wc + (size_t)((((c << 2) + w) << 1)) * (20 * 512) + (L << 3);
    const _Float16* wp1 = wp0 + 20 * 512;
#pragma unroll
    for (int n = 0; n < 2; ++n)
#pragma unroll
        for (int kt = 0; kt < 16; ++kt) {
            f32x4 v = *reinterpret_cast<const f32x4*>((n ? wp1 : wp0) + (kt << 9));
            *reinterpret_cast<f32x4*>(wl + ((((w << 1) + n) * 16 + kt) << 10) + (L << 4)) = v;
        }
    V16 wx[2][4];
#pragma unroll
    for (int n = 0; n < 2; ++n)
#pragma unroll
        for (int j = 0; j < 4; ++j)
            wx[n][j].f = *reinterpret_cast<const f32x4*>((n ? wp1 : wp0) + ((16 + j) << 9));

    // ---- per-thread cell-state mapping: thread owns h/c at (bl, j0), (bl, j0+1)
    const int bl = tid >> 4;
    const int j0 = (tid << 1) & 31;
    const float bi0 = bias[hcol0 + j0],         bi1 = bias[hcol0 + j0 + 1];
    const float bf0 = bias[512  + hcol0 + j0],  bf1 = bias[512  + hcol0 + j0 + 1];
    const float bg0 = bias[1024 + hcol0 + j0],  bg1 = bias[1024 + hcol0 + j0 + 1];
    const float bo0 = bias[1536 + hcol0 + j0],  bo1 = bias[1536 + hcol0 + j0 + 1];
    float cc0 = 0.f, cc1 = 0.f;

    const int arow = L & 15;
    const int agrp = L >> 4;
    const int ard  = arow << 10;
    const int asw  = (arow & 7) << 4;

    // ---- x fragments for t=0 (3 main tiles + tail tile)
    V16 xf[3], xt;
    {
        const _Float16* xp = xb3 + ((size_t)r * 3) * 512 + (L << 3);
#pragma unroll
        for (int j = 0; j < 3; ++j) xf[j].f = *reinterpret_cast<const f32x4*>(xp + j * 512);
        unsigned long long tv = *reinterpret_cast<const unsigned long long*>(
            xtl + (size_t)(brow0 + arow) * 4);
        xt.q[0] = (agrp == 0) ? tv : 0ull;
        xt.q[1] = 0ull;
    }

    for (int t = 0; t < S_; ++t) {
        // ---- 1. x-part MFMA (4 tiles; independent of h)
        f32x4 a00 = {0,0,0,0}, a01 = {0,0,0,0}, a10 = {0,0,0,0}, a11 = {0,0,0,0};
#pragma unroll
        for (int j = 0; j < 4; ++j) {
            half8 a = (j < 3) ? xf[j].h : xt.h;
            if (j & 1) {
                a01 = __builtin_amdgcn_mfma_f32_16x16x32_f16(a, wx[0][j].h, a01, 0, 0, 0);
                a11 = __builtin_amdgcn_mfma_f32_16x16x32_f16(a, wx[1][j].h, a11, 0, 0, 0);
            } else {
                a00 = __builtin_amdgcn_mfma_f32_16x16x32_f16(a, wx[0][j].h, a00, 0, 0, 0);
                a10 = __builtin_amdgcn_mfma_f32_16x16x32_f16(a, wx[1][j].h, a10, 0, 0, 0);
            }
        }

        V16 bp[8][2];                      // kt 0..7 B-frags (iteration-local)
        if (t > 0) {
            // ---- 2. B-fragment preread: idle LDS port during the poll
#pragma unroll
            for (int kt = 0; kt < 8; ++kt) {
                bp[kt][0].f = *reinterpret_cast<const f32x4*>(
                    wl + (((w << 5) + kt) << 10) + (L << 4));
                bp[kt][1].f = *reinterpret_cast<const f32x4*>(
                    wl + (((w << 5) + 16 + kt) << 10) + (L << 4));
            }

            // ---- 3. retry-load tagged h words until tag==t, then stage to LDS
            const unsigned long long* hq = hbt + ((size_t)(t & 1) << 16) + ((size_t)brow0 << 8);
            const unsigned tag = (unsigned)t;
            unsigned long long vv[16];
            int rounds = 0;
            bool again = true;
            while (again) {
#pragma unroll
                for (int j = 0; j < 16; ++j)
                    vv[j] = __hip_atomic_load(hq + (j << 8) + tid,
                                              __ATOMIC_RELAXED, __HIP_MEMORY_SCOPE_AGENT);
                again = false;
#pragma unroll
                for (int j = 0; j < 16; ++j) again |= ((unsigned)vv[j] != tag);
                if (++rounds > 4000000) break;   // safety valve
            }
            __builtin_amdgcn_sched_barrier(0);
            // stage: row j, col-pair tid (u32 of 2 halfs), XOR-swizzled granules
#pragma unroll
            for (int j = 0; j < 16; ++j) {
                unsigned pack = (unsigned)(vv[j] >> 32);
                *reinterpret_cast<unsigned*>(
                    al + (j << 10) + ((((tid >> 2) ^ (j & 7))) << 4) + ((tid & 3) << 2)) = pack;
            }
        }

        // ---- 4. x prefetch for t+1, issued BEFORE barrier 1: flight spans the
        //         whole h-MFMA + elementwise phase; never drained (raw barriers)
        V16 xn[3], xnt;
        {
            const int tn = (t + 1) & (S_ - 1);
            const _Float16* xp = xb3 + (((size_t)tn * 16 + r) * 3) * 512 + (L << 3);
#pragma unroll
            for (int j = 0; j < 3; ++j) xn[j].f = *reinterpret_cast<const f32x4*>(xp + j * 512);
            unsigned long long tv = *reinterpret_cast<const unsigned long long*>(
                xtl + ((size_t)tn * 256 + brow0 + arow) * 4);
            xnt.q[0] = (agrp == 0) ? tv : 0ull;
            xnt.q[1] = 0ull;
        }

        BAR_LGKM();                        // barrier 1: A tile ready (LDS-only)

        // ---- 5. h-part MFMA: A from swizzled LDS; B kt<8 from regs, kt>=8 from LDS
        if (t > 0) {
#pragma unroll
            for (int kt = 0; kt < 16; ++kt) {
                V16 av, b0, b1;
                av.f = *reinterpret_cast<const f32x4*>(
                    al + ard + ((((kt << 2) + agrp) << 4) ^ asw));
                if (kt < 8) {
                    b0 = bp[kt][0];
                    b1 = bp[kt][1];
                } else {
                    b0.f = *reinterpret_cast<const f32x4*>(
                        wl + (((w << 5) + kt) << 10) + (L << 4));
                    b1.f = *reinterpret_cast<const f32x4*>(
                        wl + (((w << 5) + 16 + kt) << 10) + (L << 4));
                }
                if (kt & 1) {
                    a01 = __builtin_amdgcn_mfma_f32_16x16x32_f16(av.h, b0.h, a01, 0, 0, 0);
                    a11 = __builtin_amdgcn_mfma_f32_16x16x32_f16(av.h, b1.h, a11, 0, 0, 0);
                } else {
                    a00 = __builtin_amdgcn_mfma_f32_16x16x32_f16(av.h, b0.h, a00, 0, 0, 0);
                    a10 = __builtin_amdgcn_mfma_f32_16x16x32_f16(av.h, b1.h, a10, 0, 0, 0);
                }
            }
        }
        f32x4 g0 = a00 + a01;
        f32x4 g1 = a10 + a11;
        {
            const int grb = agrp << 2;     // C/D: col=lane&15, row=(lane>>4)*4+reg
            const int gc  = L & 15;
#pragma unroll
            for (int rr = 0; rr < 4; ++rr) {
                gbuf[w][grb + rr][gc]      = g0[rr];
                gbuf[w][grb + rr][16 + gc] = g1[rr];
            }
        }

        BAR_LGKM();                        // barrier 2: gates ready (LDS-only)

        // ---- 6. elementwise cell update + tagged publish (fire-and-forget)
        float i0 = gbuf[0][bl][j0]     + bi0, i1 = gbuf[0][bl][j0 + 1] + bi1;
        float f0 = gbuf[1][bl][j0]     + bf0, f1 = gbuf[1][bl][j0 + 1] + bf1;
        float gg0= gbuf[2][bl][j0]     + bg0, gg1= gbuf[2][bl][j0 + 1] + bg1;
        float o0 = gbuf[3][bl][j0]     + bo0, o1 = gbuf[3][bl][j0 + 1] + bo1;
        float si0 = 1.f / (1.f + __expf(-i0));
        float sf0 = 1.f / (1.f + __expf(-f0));
        float so0 = 1.f / (1.f + __expf(-o0));
        float tg0 = tanhf(gg0);
        float si1 = 1.f / (1.f + __expf(-i1));
        float sf1 = 1.f / (1.f + __expf(-f1));
        float so1 = 1.f / (1.f + __expf(-o1));
        float tg1 = tanhf(gg1);
        cc0 = sf0 * cc0 + si0 * tg0;
        cc1 = sf1 * cc1 + si1 * tg1;
        float h0 = so0 * tanhf(cc0);
        float h1 = so1 * tanhf(cc1);

        if (t == S_ - 1) {
            float* op = out + (size_t)(brow0 + bl) * H_ + hcol0 + j0;
            op[0] = h0; op[1] = h1;
        } else {
            _Float16 hh0 = (_Float16)h0, hh1 = (_Float16)h1;
            unsigned pack = ((unsigned)*(unsigned short*)&hh1 << 16)
                          |  (unsigned)*(unsigned short*)&hh0;
            unsigned long long word = ((unsigned long long)pack << 32)
                                    |  (unsigned long long)(unsigned)(t + 1);
            __hip_atomic_store(hbt + ((size_t)((t + 1) & 1) << 16)
                                   + ((size_t)(brow0 + bl) << 8) + (c << 4) + (tid & 15),
                               word, __ATOMIC_RELAXED, __HIP_MEMORY_SCOPE_AGENT);
        }

        // rotate x prefetch
#pragma unroll
        for (int j = 0; j < 3; ++j) xf[j] = xn[j];
        xt = xnt;
    }
}

// ---------------------------------------------------------------- launch
extern "C" void kernel_launch(void* const* d_in, const int* in_sizes, int n_in,
                              void* d_out, int out_size, void* d_ws, size_t ws_size,
                              hipStream_t stream) {
    (void)in_sizes; (void)n_in; (void)out_size;
    if (ws_size < WS_NEED) return;

    const int*   sent = (const int*)d_in[0];
    const float* emb  = (const float*)d_in[1];
    const float* Wih  = (const float*)d_in[2];
    const float* Whh  = (const float*)d_in[3];
    const float* bih  = (const float*)d_in[4];
    const float* bhh  = (const float*)d_in[5];

    char* ws = (char*)d_ws;
    _Float16*           Wc   = (_Float16*)(ws + OFF_WC);
    unsigned long long* hbt  = (unsigned long long*)(ws + OFF_HBT);
    _Float16*           xb3  = (_Float16*)(ws + OFF_XB3);
    _Float16*           xtl  = (_Float16*)(ws + OFF_XTL);
    float*              bias = (float*)(ws + OFF_BIAS);

    (void)hipFuncSetAttribute(reinterpret_cast<const void*>(lstm_persist),
                              hipFuncAttributeMaxDynamicSharedMemorySize, LDS_TOT);

    (void)hipMemsetAsync(hbt, 0, 2 * 256 * 256 * sizeof(unsigned long long), stream);

    prep_wc4<<<(16 * 4 * 2 * 20 * 64 * 8) / 256, 256, 0, stream>>>(Wih, Whh, bih, bhh, Wc, bias);
    prep_x3<<<(S_ * 16 * 3 * 512) / 256, 256, 0, stream>>>(sent, emb, xb3);
    prep_xtail<<<(S_ * B_ * 4) / 256, 256, 0, stream>>>(sent, emb, xtl);
    lstm_persist<<<256, 256, LDS_TOT, stream>>>(Wc, hbt, xb3, xtl, bias, (float*)d_out);
}

// Round 15
// 1283.692 us; speedup vs baseline: 1.6539x; 1.0181x over previous
//
#include <hip/hip_runtime.h>
#include <stdint.h>

// Problem constants
#define B_  256
#define S_  512
#define E_  100
#define H_  512
#define G_  2048          // 4H
#define KH_ 512

typedef _Float16 half8 __attribute__((ext_vector_type(8)));
typedef float    f32x4 __attribute__((ext_vector_type(4)));
union V16 { f32x4 f; half8 h; unsigned long long q[2]; };

// ws layout (bytes)
#define OFF_WC   0u          // Wc [c16][w4][n2][s20][L64][e8] f16 : 2,621,440
#define OFF_HBT  2621440u    // hbt [2][256 b][256 cp] u64 tagged-h : 1,048,576
#define OFF_XB3  3670016u    // xb3 [t512][rg16][j3][L64][e8] f16   : 25,165,824
#define OFF_XTL  28835840u   // xtl [t512][b256][e4] f16            : 1,048,576
#define OFF_BIAS 29884416u   // [G] f32                             : 8,192
#define WS_NEED  29892608u

// LDS carve (dynamic) — full W h-part in LDS
#define LDS_W   131072       // [w4][n2][kt16][L64][16B]
#define LDS_A   16384        // h A-tile [16 rows][512 halfs], XOR-swizzled
#define LDS_G   8448         // float[4][16][33]
#define LDS_TOT (LDS_W + LDS_A + LDS_G)   // 155,904

// ---------------------------------------------------------------- prep: W (fragment-major) + bias
__global__ void prep_wc4(const float* __restrict__ Wih, const float* __restrict__ Whh,
                         const float* __restrict__ bih, const float* __restrict__ bhh,
                         _Float16* __restrict__ Wc, float* __restrict__ bias) {
    int idx = blockIdx.x * 256 + threadIdx.x;     // < 1,310,720
    int e  = idx & 7;
    int L  = (idx >> 3) & 63;
    int q  = idx >> 9;                            // < 2560
    int s  = q % 20;
    int qq = q / 20;
    int n  = qq & 1;
    int w  = (qq >> 1) & 3;
    int c  = qq >> 3;
    int g  = (w << 9) + (c << 5) + (n << 4) + (L & 15);
    int kl = ((L >> 4) << 3) + e;
    float v = 0.f;
    if (s < 16) {
        v = Whh[g * KH_ + (s << 5) + kl];
    } else {
        int xk = (s < 19) ? ((s - 16) << 5) + kl : 96 + kl;
        if (xk < E_) v = Wih[g * E_ + xk];
    }
    Wc[idx] = (_Float16)v;
    if (idx < G_) bias[idx] = bih[idx] + bhh[idx];
}

// ---------------------------------------------------------------- prep: x main (k 0..95, fragment-major)
__global__ void prep_x3(const int* __restrict__ sent, const float* __restrict__ emb,
                        _Float16* __restrict__ xb3) {
    size_t idx = (size_t)blockIdx.x * 256 + threadIdx.x;   // < 12,582,912
    int e  = (int)(idx & 7);
    int L  = (int)((idx >> 3) & 63);
    int q  = (int)(idx >> 9);
    int j  = q % 3;
    int qq = q / 3;
    int rg = qq & 15;
    int t  = qq >> 4;
    int b  = (rg << 4) + (L & 15);
    int k  = (j << 5) + ((L >> 4) << 3) + e;     // < 96 < E_
    int tok = sent[b * S_ + t];
    xb3[idx] = (_Float16)emb[(size_t)tok * E_ + k];
}

// ---------------------------------------------------------------- prep: x tail (k 96..99)
__global__ void prep_xtail(const int* __restrict__ sent, const float* __restrict__ emb,
                           _Float16* __restrict__ xtl) {
    int idx = blockIdx.x * 256 + threadIdx.x;    // < 524,288
    int e = idx & 3;
    int b = (idx >> 2) & 255;
    int t = idx >> 10;
    int tok = sent[b * S_ + t];
    xtl[idx] = (_Float16)emb[(size_t)tok * E_ + 96 + e];
}

// ---------------------------------------------------------------- persistent LSTM
// Final kernel (= round-12 best, 1286us measured). 256 blocks = 16 rows x 16
// hcol-tiles; W h-part in LDS; h exchange via self-validating tagged u64
// words (relaxed agent atomics, LLC-direct, fire-and-forget publish — no
// fences/releases/drains anywhere in the loop). B-fragments kt 0..7 preread
// during the poll window. Parity double-buffer + per-call memset kill all
// overwrite/stale races; step time is bounded by the LLC latency chain.
__global__ __launch_bounds__(256, 1) void lstm_persist(
    const _Float16* __restrict__ Wc, unsigned long long* __restrict__ hbt,
    const _Float16* __restrict__ xb3, const _Float16* __restrict__ xtl,
    const float* __restrict__ bias, float* __restrict__ out)
{
    extern __shared__ __align__(16) char smem[];
    char* wl = smem;                       // W h-part fragments
    char* al = smem + LDS_W;               // A tile (swizzled)
    float (*gbuf)[16][33] = reinterpret_cast<float(*)[16][33]>(smem + LDS_W + LDS_A);

    const int tid = threadIdx.x;
    const int L   = tid & 63;
    const int w   = tid >> 6;              // wave = gate type (0:i 1:f 2:g 3:o)
    const int bx  = blockIdx.x;
    const int xcd = bx & 7;                // XCD-aware swizzle (perf heuristic)
    const int kk_ = bx >> 3;
    const int r   = (xcd << 1) | (kk_ >> 4);   // batch-row 0..15
    const int c   = kk_ & 15;                  // hcol-tile 0..15
    const int brow0 = r << 4;
    const int hcol0 = c << 5;

    // ---- W preload: slots 0..15 (h) -> LDS; slots 16..19 (x) -> regs
    const _Float16* wp0 = Wc + (size_t)((((c << 2) + w) << 1)) * (20 * 512) + (L << 3);
    const _Float16* wp1 = wp0 + 20 * 512;
#pragma unroll
    for (int n = 0; n < 2; ++n)
#pragma unroll
        for (int kt = 0; kt < 16; ++kt) {
            f32x4 v = *reinterpret_cast<const f32x4*>((n ? wp1 : wp0) + (kt << 9));
            *reinterpret_cast<f32x4*>(wl + ((((w << 1) + n) * 16 + kt) << 10) + (L << 4)) = v;
        }
    V16 wx[2][4];
#pragma unroll
    for (int n = 0; n < 2; ++n)
#pragma unroll
        for (int j = 0; j < 4; ++j)
            wx[n][j].f = *reinterpret_cast<const f32x4*>((n ? wp1 : wp0) + ((16 + j) << 9));

    // ---- per-thread cell-state mapping: thread owns h/c at (bl, j0), (bl, j0+1)
    const int bl = tid >> 4;
    const int j0 = (tid << 1) & 31;
    const float bi0 = bias[hcol0 + j0],         bi1 = bias[hcol0 + j0 + 1];
    const float bf0 = bias[512  + hcol0 + j0],  bf1 = bias[512  + hcol0 + j0 + 1];
    const float bg0 = bias[1024 + hcol0 + j0],  bg1 = bias[1024 + hcol0 + j0 + 1];
    const float bo0 = bias[1536 + hcol0 + j0],  bo1 = bias[1536 + hcol0 + j0 + 1];
    float cc0 = 0.f, cc1 = 0.f;

    const int arow = L & 15;
    const int agrp = L >> 4;
    const int ard  = arow << 10;
    const int asw  = (arow & 7) << 4;

    // ---- x fragments for t=0 (3 main tiles + tail tile)
    V16 xf[3], xt;
    {
        const _Float16* xp = xb3 + ((size_t)r * 3) * 512 + (L << 3);
#pragma unroll
        for (int j = 0; j < 3; ++j) xf[j].f = *reinterpret_cast<const f32x4*>(xp + j * 512);
        unsigned long long tv = *reinterpret_cast<const unsigned long long*>(
            xtl + (size_t)(brow0 + arow) * 4);
        xt.q[0] = (agrp == 0) ? tv : 0ull;
        xt.q[1] = 0ull;
    }

    for (int t = 0; t < S_; ++t) {
        // ---- 1. x-part MFMA (4 tiles; independent of h)
        f32x4 a00 = {0,0,0,0}, a01 = {0,0,0,0}, a10 = {0,0,0,0}, a11 = {0,0,0,0};
#pragma unroll
        for (int j = 0; j < 4; ++j) {
            half8 a = (j < 3) ? xf[j].h : xt.h;
            if (j & 1) {
                a01 = __builtin_amdgcn_mfma_f32_16x16x32_f16(a, wx[0][j].h, a01, 0, 0, 0);
                a11 = __builtin_amdgcn_mfma_f32_16x16x32_f16(a, wx[1][j].h, a11, 0, 0, 0);
            } else {
                a00 = __builtin_amdgcn_mfma_f32_16x16x32_f16(a, wx[0][j].h, a00, 0, 0, 0);
                a10 = __builtin_amdgcn_mfma_f32_16x16x32_f16(a, wx[1][j].h, a10, 0, 0, 0);
            }
        }

        V16 bp[8][2];                      // kt 0..7 B-frags (iteration-local)
        if (t > 0) {
            // ---- 2. B-fragment preread: uses the idle LDS port during the poll
#pragma unroll
            for (int kt = 0; kt < 8; ++kt) {
                bp[kt][0].f = *reinterpret_cast<const f32x4*>(
                    wl + (((w << 5) + kt) << 10) + (L << 4));
                bp[kt][1].f = *reinterpret_cast<const f32x4*>(
                    wl + (((w << 5) + 16 + kt) << 10) + (L << 4));
            }

            // ---- 3. retry-load tagged h words until tag==t, then stage to LDS
            const unsigned long long* hq = hbt + ((size_t)(t & 1) << 16) + ((size_t)brow0 << 8);
            const unsigned tag = (unsigned)t;
            unsigned long long vv[16];
            int rounds = 0;
            bool again = true;
            while (again) {
#pragma unroll
                for (int j = 0; j < 16; ++j)
                    vv[j] = __hip_atomic_load(hq + (j << 8) + tid,
                                              __ATOMIC_RELAXED, __HIP_MEMORY_SCOPE_AGENT);
                again = false;
#pragma unroll
                for (int j = 0; j < 16; ++j) again |= ((unsigned)vv[j] != tag);
                if (++rounds > 4000000) break;   // safety valve
            }
            __builtin_amdgcn_sched_barrier(0);
            // stage: row j, col-pair tid (u32 of 2 halfs), XOR-swizzled granules
#pragma unroll
            for (int j = 0; j < 16; ++j) {
                unsigned pack = (unsigned)(vv[j] >> 32);
                *reinterpret_cast<unsigned*>(
                    al + (j << 10) + ((((tid >> 2) ^ (j & 7))) << 4) + ((tid & 3) << 2)) = pack;
            }
        }
        __syncthreads();                   // barrier 1: A tile ready

        // ---- 4. h-part MFMA: A from swizzled LDS; B kt<8 from regs, kt>=8 from LDS
        if (t > 0) {
#pragma unroll
            for (int kt = 0; kt < 16; ++kt) {
                V16 av, b0, b1;
                av.f = *reinterpret_cast<const f32x4*>(
                    al + ard + ((((kt << 2) + agrp) << 4) ^ asw));
                if (kt < 8) {
                    b0 = bp[kt][0];
                    b1 = bp[kt][1];
                } else {
                    b0.f = *reinterpret_cast<const f32x4*>(
                        wl + (((w << 5) + kt) << 10) + (L << 4));
                    b1.f = *reinterpret_cast<const f32x4*>(
                        wl + (((w << 5) + 16 + kt) << 10) + (L << 4));
                }
                if (kt & 1) {
                    a01 = __builtin_amdgcn_mfma_f32_16x16x32_f16(av.h, b0.h, a01, 0, 0, 0);
                    a11 = __builtin_amdgcn_mfma_f32_16x16x32_f16(av.h, b1.h, a11, 0, 0, 0);
                } else {
                    a00 = __builtin_amdgcn_mfma_f32_16x16x32_f16(av.h, b0.h, a00, 0, 0, 0);
                    a10 = __builtin_amdgcn_mfma_f32_16x16x32_f16(av.h, b1.h, a10, 0, 0, 0);
                }
            }
        }
        f32x4 g0 = a00 + a01;
        f32x4 g1 = a10 + a11;
        {
            const int grb = agrp << 2;     // C/D: col=lane&15, row=(lane>>4)*4+reg
            const int gc  = L & 15;
#pragma unroll
            for (int rr = 0; rr < 4; ++rr) {
                gbuf[w][grb + rr][gc]      = g0[rr];
                gbuf[w][grb + rr][16 + gc] = g1[rr];
            }
        }

        // ---- 5. prefetch next step's x fragments (land during barrier+elementwise)
        V16 xn[3], xnt;
        {
            const int tn = (t + 1) & (S_ - 1);
            const _Float16* xp = xb3 + (((size_t)tn * 16 + r) * 3) * 512 + (L << 3);
#pragma unroll
            for (int j = 0; j < 3; ++j) xn[j].f = *reinterpret_cast<const f32x4*>(xp + j * 512);
            unsigned long long tv = *reinterpret_cast<const unsigned long long*>(
                xtl + ((size_t)tn * 256 + brow0 + arow) * 4);
            xnt.q[0] = (agrp == 0) ? tv : 0ull;
            xnt.q[1] = 0ull;
        }
        __syncthreads();                   // barrier 2: gates ready

        // ---- 6. elementwise cell update + tagged publish (fire-and-forget)
        float i0 = gbuf[0][bl][j0]     + bi0, i1 = gbuf[0][bl][j0 + 1] + bi1;
        float f0 = gbuf[1][bl][j0]     + bf0, f1 = gbuf[1][bl][j0 + 1] + bf1;
        float gg0= gbuf[2][bl][j0]     + bg0, gg1= gbuf[2][bl][j0 + 1] + bg1;
        float o0 = gbuf[3][bl][j0]     + bo0, o1 = gbuf[3][bl][j0 + 1] + bo1;
        float si0 = 1.f / (1.f + __expf(-i0));
        float sf0 = 1.f / (1.f + __expf(-f0));
        float so0 = 1.f / (1.f + __expf(-o0));
        float tg0 = tanhf(gg0);
        float si1 = 1.f / (1.f + __expf(-i1));
        float sf1 = 1.f / (1.f + __expf(-f1));
        float so1 = 1.f / (1.f + __expf(-o1));
        float tg1 = tanhf(gg1);
        cc0 = sf0 * cc0 + si0 * tg0;
        cc1 = sf1 * cc1 + si1 * tg1;
        float h0 = so0 * tanhf(cc0);
        float h1 = so1 * tanhf(cc1);

        if (t == S_ - 1) {
            float* op = out + (size_t)(brow0 + bl) * H_ + hcol0 + j0;
            op[0] = h0; op[1] = h1;
        } else {
            _Float16 hh0 = (_Float16)h0, hh1 = (_Float16)h1;
            unsigned pack = ((unsigned)*(unsigned short*)&hh1 << 16)
                          |  (unsigned)*(unsigned short*)&hh0;
            unsigned long long word = ((unsigned long long)pack << 32)
                                    |  (unsigned long long)(unsigned)(t + 1);
            __hip_atomic_store(hbt + ((size_t)((t + 1) & 1) << 16)
                                   + ((size_t)(brow0 + bl) << 8) + (c << 4) + (tid & 15),
                               word, __ATOMIC_RELAXED, __HIP_MEMORY_SCOPE_AGENT);
        }

        // rotate x prefetch
#pragma unroll
        for (int j = 0; j < 3; ++j) xf[j] = xn[j];
        xt = xnt;
    }
}

// ---------------------------------------------------------------- launch
extern "C" void kernel_launch(void* const* d_in, const int* in_sizes, int n_in,
                              void* d_out, int out_size, void* d_ws, size_t ws_size,
                              hipStream_t stream) {
    (void)in_sizes; (void)n_in; (void)out_size;
    if (ws_size < WS_NEED) return;

    const int*   sent = (const int*)d_in[0];
    const float* emb  = (const float*)d_in[1];
    const float* Wih  = (const float*)d_in[2];
    const float* Whh  = (const float*)d_in[3];
    const float* bih  = (const float*)d_in[4];
    const float* bhh  = (const float*)d_in[5];

    char* ws = (char*)d_ws;
    _Float16*           Wc   = (_Float16*)(ws + OFF_WC);
    unsigned long long* hbt  = (unsigned long long*)(ws + OFF_HBT);
    _Float16*           xb3  = (_Float16*)(ws + OFF_XB3);
    _Float16*           xtl  = (_Float16*)(ws + OFF_XTL);
    float*              bias = (float*)(ws + OFF_BIAS);

    (void)hipFuncSetAttribute(reinterpret_cast<const void*>(lstm_persist),
                              hipFuncAttributeMaxDynamicSharedMemorySize, LDS_TOT);

    (void)hipMemsetAsync(hbt, 0, 2 * 256 * 256 * sizeof(unsigned long long), stream);

    prep_wc4<<<(16 * 4 * 2 * 20 * 64 * 8) / 256, 256, 0, stream>>>(Wih, Whh, bih, bhh, Wc, bias);
    prep_x3<<<(S_ * 16 * 3 * 512) / 256, 256, 0, stream>>>(sent, emb, xb3);
    prep_xtail<<<(S_ * B_ * 4) / 256, 256, 0, stream>>>(sent, emb, xtl);
    lstm_persist<<<256, 256, LDS_TOT, stream>>>(Wc, hbt, xb3, xtl, bias, (float*)d_out);
}